// Round 7
// baseline (167.547 us; speedup 1.0000x reference)
//
#include <hip/hip_runtime.h>
#include <hip/hip_bf16.h>
#include <cstdint>
#include <math.h>

#define S_LEN 2048
#define DM 1024
#define NQKV 1536
#define MROWS 4096   // B * S
#define BKT 64

typedef __attribute__((ext_vector_type(8))) short short8;
typedef __attribute__((ext_vector_type(4))) float f32x4;
typedef __attribute__((ext_vector_type(16))) float f32x16;

// 0.125 (1/sqrt(64)) * log2(e), folded into Q at RoPE time
#define QFOLD 0.18033688011112042f

__device__ __forceinline__ short f2bf(float x) {
  union { float f; uint32_t u; } v; v.f = x;
  uint32_t r = (v.u + 0x7fffu + ((v.u >> 16) & 1u)) >> 16;
  return (short)(uint16_t)r;
}

__device__ __forceinline__ uint32_t pk2(float a, float b) {
  __hip_bfloat162 h = __float22bfloat162_rn(make_float2(a, b));
  union { __hip_bfloat162 h2; uint32_t u; } cv; cv.h2 = h;
  return cv.u;
}

// ---------------- merged prep: x->bf16 convert + 4 weight transposes + rope table ----------------
// blocks [0,4096): convert; [4096,4352): Wq; [4352,4416): Wk; [4416,4480): Wv;
// [4480,4736): Wo; [4736,4800): cos/sin table tab[s*32+j] (same cosf/sinf data
// path as the original rope kernel -> bit-identical rope values).
__global__ __launch_bounds__(256) void prep(const float* __restrict__ x,
    const float* __restrict__ Wq, const float* __restrict__ Wk,
    const float* __restrict__ Wv, const float* __restrict__ Wo,
    short* __restrict__ Xb, short* __restrict__ WcatT, short* __restrict__ WoT,
    float2* __restrict__ tab) {
  __shared__ short T[64 * 72];
  const int bb = blockIdx.x;
  const int tid = threadIdx.x;
  if (bb < 4096) {                       // fp32 -> bf16 vectorized convert
    const int i = bb * 256 + tid;        // exactly MROWS*DM/4 elements
    float4 v = ((const float4*)x)[i];
    short4 o;
    o.x = f2bf(v.x); o.y = f2bf(v.y); o.z = f2bf(v.z); o.w = f2bf(v.w);
    ((short4*)Xb)[i] = o;
    return;
  }
  if (bb >= 4736) {                      // rope cos/sin table: 2048 x 32 entries
    const int gid = (bb - 4736) * 256 + tid;   // [0,16384)
    #pragma unroll
    for (int e = 0; e < 4; ++e) {
      const int ii = gid + e * 16384;          // [0,65536)
      const int s = ii >> 5, j = ii & 31;
      const float inv = exp2f(-(float)j * 0.41524101186092029f);  // log2(10000)/32
      const float ang = (float)s * inv;
      tab[ii] = make_float2(cosf(ang), sinf(ang));
    }
    return;
  }
  const float* src; short* dst; int R, C, t2 = bb - 4096;
  if (t2 < 256)      { src = Wq; dst = WcatT;                        R = 1024; C = 1024; }
  else if (t2 < 320) { t2 -= 256; src = Wk; dst = WcatT + (size_t)1024*1024; R = 1024; C = 256; }
  else if (t2 < 384) { t2 -= 320; src = Wv; dst = WcatT + (size_t)1280*1024; R = 1024; C = 256; }
  else               { t2 -= 384; src = Wo; dst = WoT;               R = 1024; C = 1024; }
  const int r0 = (t2 & 15) * 64, c0 = (t2 >> 4) * 64;
  #pragma unroll
  for (int i = 0; i < 4; ++i) {
    int chunk = tid + i * 256;
    int r = chunk >> 4, cc = (chunk & 15) * 4;
    float4 v = *(const float4*)&src[(size_t)(r0 + r) * C + c0 + cc];
    T[(cc + 0) * 72 + r] = f2bf(v.x);
    T[(cc + 1) * 72 + r] = f2bf(v.y);
    T[(cc + 2) * 72 + r] = f2bf(v.z);
    T[(cc + 3) * 72 + r] = f2bf(v.w);
  }
  __syncthreads();
  #pragma unroll
  for (int i = 0; i < 2; ++i) {
    int chunk = tid + i * 256;
    int rr = chunk >> 3, kk = (chunk & 7) * 8;
    *(uint4*)&dst[(size_t)(c0 + rr) * R + r0 + kk] = *(uint4*)&T[rr * 72 + kk];
  }
}

// ---------------- bf16 MFMA GEMM, m97-style staging, tile-templated (plain fp32 C) ----------------
template<int BMT, int BNT>
__global__ __launch_bounds__(256) void gemm_bf16_t(const short* __restrict__ A,
    const short* __restrict__ BT, float* __restrict__ C, int M, int N, int K) {
  constexpr int MI = BMT / 32, NI = BNT / 32;
  __shared__ short As[BMT * BKT];
  __shared__ short Bs[BNT * BKT];
  const int tid = threadIdx.x;
  const int wave = tid >> 6, lane = tid & 63;
  const int quad = lane >> 4, l15 = lane & 15;
  const int wm = (wave >> 1) * (BMT / 2), wn = (wave & 1) * (BNT / 2);
  const int m0 = blockIdx.y * BMT, n0 = blockIdx.x * BNT;
  const int rA = wave * (BMT / 4) + (lane >> 3);
  const int rB = wave * (BNT / 4) + (lane >> 3);
  const int scol = (lane & 7) * 8;

  f32x4 acc[MI][NI] = {};

  for (int k0 = 0; k0 < K; k0 += BKT) {
    __syncthreads();
    #pragma unroll
    for (int j = 0; j < MI; ++j)
      __builtin_amdgcn_global_load_lds(
          (const __attribute__((address_space(1))) void*)&A[(size_t)(m0 + rA + j * 8) * K + k0 + scol],
          (__attribute__((address_space(3))) void*)&As[(wave * MI + j) * 512],
          16, 0, 0);
    #pragma unroll
    for (int j = 0; j < NI; ++j)
      __builtin_amdgcn_global_load_lds(
          (const __attribute__((address_space(1))) void*)&BT[(size_t)(n0 + rB + j * 8) * K + k0 + scol],
          (__attribute__((address_space(3))) void*)&Bs[(wave * NI + j) * 512],
          16, 0, 0);
    __syncthreads();
    #pragma unroll
    for (int ks = 0; ks < 2; ++ks) {
      short8 af[MI], bfr[NI];
      #pragma unroll
      for (int mi = 0; mi < MI; ++mi)
        af[mi] = *(const short8*)&As[(wm + mi*16 + l15)*BKT + ks*32 + quad*8];
      #pragma unroll
      for (int ni = 0; ni < NI; ++ni)
        bfr[ni] = *(const short8*)&Bs[(wn + ni*16 + l15)*BKT + ks*32 + quad*8];
      #pragma unroll
      for (int mi = 0; mi < MI; ++mi)
        #pragma unroll
        for (int ni = 0; ni < NI; ++ni)
          acc[mi][ni] = __builtin_amdgcn_mfma_f32_16x16x32_bf16(af[mi], bfr[ni], acc[mi][ni], 0, 0, 0);
    }
  }
  #pragma unroll
  for (int mi = 0; mi < MI; ++mi)
    #pragma unroll
    for (int ni = 0; ni < NI; ++ni)
      #pragma unroll
      for (int r = 0; r < 4; ++r)
        C[(size_t)(m0 + wm + mi*16 + quad*4 + r)*N + (n0 + wn + ni*16 + l15)] = acc[mi][ni][r];
}

// ---------------- QKV GEMM with fused RoPE + fused V-transpose epilogue ----------------
// 64x128 tile. Q blocks: rope*QFOLD. K blocks: rope + XOR-swizzle. V blocks:
// transpose in (dead) staging LDS and write Vt[(b*4+kvh)*64+d][s] directly,
// XOR-swizzled s^((d&7)<<3) within 64-s chunks — replaces the transpose_v kernel.
__global__ __launch_bounds__(256, 3) void gemm_qkv(const short* __restrict__ A,
    const short* __restrict__ BT, const float2* __restrict__ tab,
    short* __restrict__ Qb, short* __restrict__ Kb, short* __restrict__ Vt) {
  constexpr int MI = 2, NI = 4;   // 64 x 128
  __shared__ short SM[12288];     // As[64*64] @0, Bs[128*64] @4096; V-transpose T[128][80] aliases
  short* As = SM;
  short* Bs = SM + 4096;
  const int tid = threadIdx.x;
  const int wave = tid >> 6, lane = tid & 63;
  const int quad = lane >> 4, l15 = lane & 15;
  const int wm = (wave >> 1) * 32, wn = (wave & 1) * 64;
  const int m0 = blockIdx.y * 64, n0 = blockIdx.x * 128;
  const int rA = wave * 16 + (lane >> 3);
  const int rB = wave * 32 + (lane >> 3);
  const int scol = (lane & 7) * 8;

  f32x4 acc[MI][NI] = {};

  for (int k0 = 0; k0 < DM; k0 += BKT) {
    __syncthreads();
    #pragma unroll
    for (int j = 0; j < MI; ++j)
      __builtin_amdgcn_global_load_lds(
          (const __attribute__((address_space(1))) void*)&A[(size_t)(m0 + rA + j * 8) * DM + k0 + scol],
          (__attribute__((address_space(3))) void*)&As[(wave * MI + j) * 512],
          16, 0, 0);
    #pragma unroll
    for (int j = 0; j < NI; ++j)
      __builtin_amdgcn_global_load_lds(
          (const __attribute__((address_space(1))) void*)&BT[(size_t)(n0 + rB + j * 8) * DM + k0 + scol],
          (__attribute__((address_space(3))) void*)&Bs[(wave * NI + j) * 512],
          16, 0, 0);
    __syncthreads();
    #pragma unroll
    for (int ks = 0; ks < 2; ++ks) {
      short8 af[MI], bfr[NI];
      #pragma unroll
      for (int mi = 0; mi < MI; ++mi)
        af[mi] = *(const short8*)&As[(wm + mi*16 + l15)*BKT + ks*32 + quad*8];
      #pragma unroll
      for (int ni = 0; ni < NI; ++ni)
        bfr[ni] = *(const short8*)&Bs[(wn + ni*16 + l15)*BKT + ks*32 + quad*8];
      #pragma unroll
      for (int mi = 0; mi < MI; ++mi)
        #pragma unroll
        for (int ni = 0; ni < NI; ++ni)
          acc[mi][ni] = __builtin_amdgcn_mfma_f32_16x16x32_bf16(af[mi], bfr[ni], acc[mi][ni], 0, 0, 0);
    }
  }

  const int c0 = n0 + wn;                 // multiple of 64
  if (n0 < 1024) {                        // ---- Q: rope * QFOLD ----
    #pragma unroll
    for (int mi = 0; mi < MI; ++mi)
      #pragma unroll
      for (int r = 0; r < 4; ++r) {
        const int row = m0 + wm + mi*16 + quad*4 + r;
        const int s = row & (S_LEN - 1);
        #pragma unroll
        for (int ni = 0; ni < 2; ++ni) {
          const int j = ni*16 + l15;
          const float2 cn = tab[s*32 + j];
          const float x1 = acc[mi][ni][r], x2 = acc[mi][ni+2][r];
          Qb[(size_t)row*1024 + c0 + j]      = f2bf((x1*cn.x - x2*cn.y) * QFOLD);
          Qb[(size_t)row*1024 + c0 + j + 32] = f2bf((x2*cn.x + x1*cn.y) * QFOLD);
        }
      }
  } else if (n0 < 1280) {                 // ---- K: rope + XOR-swizzle ----
    const int hh = (c0 - 1024) >> 6;
    #pragma unroll
    for (int mi = 0; mi < MI; ++mi)
      #pragma unroll
      for (int r = 0; r < 4; ++r) {
        const int row = m0 + wm + mi*16 + quad*4 + r;
        const int s = row & (S_LEN - 1);
        const int sw = (s & 7) << 3;
        #pragma unroll
        for (int ni = 0; ni < 2; ++ni) {
          const int j = ni*16 + l15;
          const float2 cn = tab[s*32 + j];
          const float x1 = acc[mi][ni][r], x2 = acc[mi][ni+2][r];
          Kb[(size_t)row*256 + hh*64 + (j ^ sw)]        = f2bf(x1*cn.x - x2*cn.y);
          Kb[(size_t)row*256 + hh*64 + ((j + 32) ^ sw)] = f2bf(x2*cn.x + x1*cn.y);
        }
      }
  } else {                                // ---- V: LDS transpose -> Vt (swizzled) ----
    __syncthreads();                      // staging LDS dead; reuse as T[128 vcol][80]
    #pragma unroll
    for (int mi = 0; mi < MI; ++mi)
      #pragma unroll
      for (int ni = 0; ni < NI; ++ni) {
        short4 p;
        p.x = f2bf(acc[mi][ni][0]); p.y = f2bf(acc[mi][ni][1]);
        p.z = f2bf(acc[mi][ni][2]); p.w = f2bf(acc[mi][ni][3]);
        *(short4*)&SM[(wn + ni*16 + l15)*80 + wm + mi*16 + quad*4] = p;
      }
    __syncthreads();
    const int b_ = m0 >> 11, sbase = m0 & (S_LEN - 1);
    #pragma unroll
    for (int i = 0; i < 4; ++i) {
      const int chunk = tid + i * 256;      // [0,1024)
      const int vl = chunk >> 3;            // local vcol 0..127
      const int kk = (chunk & 7) * 8;       // 0..56
      const int vcol = (n0 - 1280) + vl;
      const int kvh = vcol >> 6, dd = vcol & 63;
      uint4 v = *(uint4*)&SM[vl*80 + kk];
      *(uint4*)&Vt[((size_t)((b_*4 + kvh)*64 + dd))*S_LEN + sbase + (kk ^ ((dd & 7) << 3))] = v;
    }
  }
}

// ---------------- causal GQA flash attention v13: heads-as-waves ----------------
// grid 512 = (b:2, kvh:4, jt:64 of 32-q tiles). Block = 256 threads = 4 waves =
// the 4 q-heads sharing one kv-head. Each wave processes its head's 32 q-rows
// against the FULL 64-kv unit (no kv split, no cross-wave combine): 16 MFMA +
// 32 exp2 per wave per barrier interval (2x fattn12). K/V staged ONCE per
// kv-group (was 4x, once per head). Ring-3 16KB bufs (48KB LDS), counted
// vmcnt. Pair-balanced dispatch: idx<256 -> jt=63-(idx>>3) (long), else
// jt=(idx>>3) (short); per-CU pair sums to a uniform 33 units; all 512 blocks
// resident from start (2 blocks/CU).
__global__ __launch_bounds__(256, 3) void fattn13(const short* __restrict__ Qb,
    const short* __restrict__ Kb, const short* __restrict__ Vt, short* __restrict__ Ctx) {
  __shared__ short SMEM[24576];   // 3 bufs x (K[64][64] @ +0, VT[64][64] @ +4096 shorts)
  const int idx = blockIdx.x;
  const int kk_ = (idx & 255) >> 3;
  const int jt  = (idx >> 8) ? kk_ : 63 - kk_;
  const int b   = (idx >> 2) & 1;
  const int kvh = idx & 3;
  const int tid = threadIdx.x, wav = tid >> 6, lane = tid & 63;
  const int l31 = lane & 31, hi = lane >> 5;
  const int h = kvh * 4 + wav;             // this wave's q-head
  const int sx = (l31 & 7) << 3;           // XOR-swizzle key (matches producers)
  const size_t qbase  = (size_t)b * S_LEN * 1024;
  const size_t kbase  = (size_t)b * S_LEN * 256;
  const size_t vtbase = (size_t)(b * 4 + kvh) * 64 * S_LEN;

  // block-wide staging: thread stages one 16B chunk per array per i_;
  // chunk c = tid + i_*256: K row c>>3, col (c&7)*8; V d-row c>>3, kv (c&7)*8.
  const short* kptr = Kb + kbase + (size_t)(tid >> 3) * 256 + kvh * 64 + (tid & 7) * 8;
  const short* vptr = Vt + vtbase + (size_t)(tid >> 3) * 2048 + (tid & 7) * 8;

#define STAGE(u) do { \
    const int bi_ = (u) % 3; \
    const short* kp_ = kptr + (size_t)(u) * 16384; \
    const short* vp_ = vptr + (u) * 64; \
    short* kd_ = &SMEM[bi_ * 8192 + tid * 8]; \
    short* vd_ = &SMEM[bi_ * 8192 + 4096 + tid * 8]; \
    _Pragma("unroll") \
    for (int i_ = 0; i_ < 2; ++i_) { \
      __builtin_amdgcn_global_load_lds((const __attribute__((address_space(1))) void*)(kp_ + i_ * 8192), \
          (__attribute__((address_space(3))) void*)(kd_ + i_ * 2048), 16, 0, 0); \
      __builtin_amdgcn_global_load_lds((const __attribute__((address_space(1))) void*)(vp_ + i_ * 65536), \
          (__attribute__((address_space(3))) void*)(vd_ + i_ * 2048), 16, 0, 0); \
    } \
  } while (0)

  const int q0 = jt * 32;
  const int ntiles = (jt >> 1) + 1;     // 64-kv units covering [0, q0+32)
  const int qg = q0 + l31;              // this lane's q column (score space)

  // Q B-frags: lane holds Q[q=l31 of tile][d = ks*16 + hi*8 + j]
  short8 qf[4];
  {
    const short* qp = &Qb[qbase + (size_t)qg * 1024 + h * 64 + hi * 8];
    #pragma unroll
    for (int ks = 0; ks < 4; ++ks) qf[ks] = *(const short8*)(qp + ks * 16);
  }

  f32x16 O0 = {}, O1 = {};
  float la0 = 0.f, la1 = 0.f, la2 = 0.f, la3 = 0.f;

  STAGE(0);
  if (ntiles > 1) STAGE(1);

  for (int t = 0; t < ntiles; ++t) {
    const int k0 = t * 64;
    const int rem = ntiles - 1 - t;
    if (rem >= 1) { asm volatile("s_waitcnt vmcnt(4)" ::: "memory"); }
    else          { asm volatile("s_waitcnt vmcnt(0)" ::: "memory"); }
    __builtin_amdgcn_sched_barrier(0);
    __builtin_amdgcn_s_barrier();
    if (t + 2 < ntiles) STAGE(t + 2);   // writes buf (t+2)%3 == (t-1)%3: reads done

    const short* ks_ = &SMEM[(t % 3) * 8192];
    const short* vs_ = &SMEM[(t % 3) * 8192 + 4096];

    // St = K Q^T over the full 64-kv unit: sc[kt][r] = S[kv=k0+kt*32+crow(r,hi)][q=qg]
    f32x16 sc[2];
    __builtin_amdgcn_s_setprio(1);
    #pragma unroll
    for (int kt = 0; kt < 2; ++kt) {
      const int r = kt * 32 + l31;
      f32x16 a = {};
      #pragma unroll
      for (int ks2 = 0; ks2 < 4; ++ks2) {
        short8 kf = *(const short8*)&ks_[r * 64 + ((ks2 * 16 + hi * 8) ^ sx)];
        a = __builtin_amdgcn_mfma_f32_32x32x16_bf16(kf, qf[ks2], a, 0, 0, 0);
      }
      sc[kt] = a;
    }
    __builtin_amdgcn_s_setprio(0);

    if (t == ntiles - 1) {
      #pragma unroll
      for (int kt = 0; kt < 2; ++kt)
        #pragma unroll
        for (int r = 0; r < 16; ++r) {
          const int kvg = k0 + kt * 32 + (r & 3) + 8 * (r >> 2) + 4 * hi;
          if (kvg > qg) sc[kt][r] = -1e30f;
        }
    }

    // no-max softmax: p = exp2(s); PV A-frags in-register (T12):
    // af[s] = P[q=l31][kv_local = s*16 + hi*8 + j], s = kt*2 + st
    short8 af[4];
    #pragma unroll
    for (int kt = 0; kt < 2; ++kt) {
      #pragma unroll
      for (int r = 0; r < 16; ++r) sc[kt][r] = exp2f(sc[kt][r]);
      la0 += (sc[kt][0] + sc[kt][1]) + (sc[kt][2] + sc[kt][3]);
      la1 += (sc[kt][4] + sc[kt][5]) + (sc[kt][6] + sc[kt][7]);
      la2 += (sc[kt][8] + sc[kt][9]) + (sc[kt][10] + sc[kt][11]);
      la3 += (sc[kt][12] + sc[kt][13]) + (sc[kt][14] + sc[kt][15]);
      #pragma unroll
      for (int st = 0; st < 2; ++st) {
        uint32_t x0 = pk2(sc[kt][st * 8 + 0], sc[kt][st * 8 + 1]);
        uint32_t x1 = pk2(sc[kt][st * 8 + 2], sc[kt][st * 8 + 3]);
        uint32_t x2 = pk2(sc[kt][st * 8 + 4], sc[kt][st * 8 + 5]);
        uint32_t x3 = pk2(sc[kt][st * 8 + 6], sc[kt][st * 8 + 7]);
        asm("v_permlane32_swap_b32 %0, %1" : "+v"(x0), "+v"(x2));
        asm("v_permlane32_swap_b32 %0, %1" : "+v"(x1), "+v"(x3));
        union { short8 s8; uint32_t u[4]; } cv;
        cv.u[0] = x0; cv.u[1] = x1; cv.u[2] = x2; cv.u[3] = x3;
        af[kt * 2 + st] = cv.s8;
      }
    }

    // O += P V over the full 64-kv unit: B-frag from V^T LDS rows d=l31 / 32+l31
    __builtin_amdgcn_s_setprio(1);
    #pragma unroll
    for (int s = 0; s < 4; ++s) {
      const int co = s * 16 + hi * 8;
      short8 bv0 = *(const short8*)&vs_[l31 * 64 + (co ^ sx)];
      O0 = __builtin_amdgcn_mfma_f32_32x32x16_bf16(af[s], bv0, O0, 0, 0, 0);
      short8 bv1 = *(const short8*)&vs_[(32 + l31) * 64 + (co ^ sx)];
      O1 = __builtin_amdgcn_mfma_f32_32x32x16_bf16(af[s], bv1, O1, 0, 0, 0);
    }
    __builtin_amdgcn_s_setprio(0);
  }

  // ---- finalize: wave owns full kv for its head -> no cross-wave combine ----
  float ll = (la0 + la1) + (la2 + la3);
  ll += __shfl_xor(ll, 32, 64);   // lane: l for q = q0 + l31 (full kv sum)
  const float inv = 1.0f / ll;
  #pragma unroll
  for (int r = 0; r < 16; ++r) {
    const int crow = (r & 3) + 8 * (r >> 2) + 4 * hi;
    const float invr = __shfl(inv, crow, 64);
    const size_t o = qbase + (size_t)(q0 + crow) * 1024 + h * 64;
    Ctx[o + l31]      = f2bf(O0[r] * invr);
    Ctx[o + 32 + l31] = f2bf(O1[r] * invr);
  }
#undef STAGE
}

extern "C" void kernel_launch(void* const* d_in, const int* in_sizes, int n_in,
                              void* d_out, int out_size, void* d_ws, size_t ws_size,
                              hipStream_t stream) {
  const float* x  = (const float*)d_in[0];
  const float* Wq = (const float*)d_in[1];
  const float* Wk = (const float*)d_in[2];
  const float* Wv = (const float*)d_in[3];
  const float* Wo = (const float*)d_in[4];
  float* out = (float*)d_out;

  char* w = (char*)d_ws;
  short*  Xb    = (short*)w;   w += (size_t)MROWS * DM * 2;
  short*  WcatT = (short*)w;   w += (size_t)NQKV * DM * 2;
  short*  WoT   = (short*)w;   w += (size_t)DM * DM * 2;
  short*  Qbuf  = (short*)w;   w += (size_t)MROWS * DM * 2;
  short*  Kbuf  = (short*)w;   w += (size_t)MROWS * 256 * 2;
  short*  Vt    = (short*)w;   w += (size_t)8 * 64 * S_LEN * 2;
  short*  Ctx   = (short*)w;   w += (size_t)MROWS * DM * 2;
  float2* tab   = (float2*)w;  w += (size_t)S_LEN * 32 * 8;

  prep<<<dim3(4800), dim3(256), 0, stream>>>(x, Wq, Wk, Wv, Wo, Xb, WcatT, WoT, tab);

  // QKV GEMM with fused rope + fused V-transpose epilogue
  gemm_qkv<<<dim3(NQKV / 128, MROWS / 64), dim3(256), 0, stream>>>(Xb, WcatT, tab, Qbuf, Kbuf, Vt);
  fattn13<<<dim3(512), dim3(256), 0, stream>>>(Qbuf, Kbuf, Vt, Ctx);
  gemm_bf16_t<64,128><<<dim3(DM / 128, MROWS / 64), dim3(256), 0, stream>>>(Ctx, WoT, out, MROWS, DM, DM);
}

// Round 9
// 166.796 us; speedup vs baseline: 1.0045x; 1.0045x over previous
//
#include <hip/hip_runtime.h>
#include <hip/hip_bf16.h>
#include <cstdint>
#include <math.h>

#define S_LEN 2048
#define DM 1024
#define NQKV 1536
#define MROWS 4096   // B * S
#define BKT 64

typedef __attribute__((ext_vector_type(8))) short short8;
typedef __attribute__((ext_vector_type(4))) float f32x4;
typedef __attribute__((ext_vector_type(16))) float f32x16;

// 0.125 (1/sqrt(64)) * log2(e), folded into Q at RoPE time
#define QFOLD 0.18033688011112042f

__device__ __forceinline__ short f2bf(float x) {
  union { float f; uint32_t u; } v; v.f = x;
  uint32_t r = (v.u + 0x7fffu + ((v.u >> 16) & 1u)) >> 16;
  return (short)(uint16_t)r;
}

__device__ __forceinline__ uint32_t pk2(float a, float b) {
  __hip_bfloat162 h = __float22bfloat162_rn(make_float2(a, b));
  union { __hip_bfloat162 h2; uint32_t u; } cv; cv.h2 = h;
  return cv.u;
}

// ---------------- merged prep: x->bf16 convert + 4 weight transposes + rope table ----------------
__global__ __launch_bounds__(256) void prep(const float* __restrict__ x,
    const float* __restrict__ Wq, const float* __restrict__ Wk,
    const float* __restrict__ Wv, const float* __restrict__ Wo,
    short* __restrict__ Xb, short* __restrict__ WcatT, short* __restrict__ WoT,
    float2* __restrict__ tab) {
  __shared__ short T[64 * 72];
  const int bb = blockIdx.x;
  const int tid = threadIdx.x;
  if (bb < 4096) {                       // fp32 -> bf16 vectorized convert
    const int i = bb * 256 + tid;        // exactly MROWS*DM/4 elements
    float4 v = ((const float4*)x)[i];
    short4 o;
    o.x = f2bf(v.x); o.y = f2bf(v.y); o.z = f2bf(v.z); o.w = f2bf(v.w);
    ((short4*)Xb)[i] = o;
    return;
  }
  if (bb >= 4736) {                      // rope cos/sin table: 2048 x 32 entries
    const int gid = (bb - 4736) * 256 + tid;   // [0,16384)
    #pragma unroll
    for (int e = 0; e < 4; ++e) {
      const int ii = gid + e * 16384;          // [0,65536)
      const int s = ii >> 5, j = ii & 31;
      const float inv = exp2f(-(float)j * 0.41524101186092029f);  // log2(10000)/32
      const float ang = (float)s * inv;
      tab[ii] = make_float2(cosf(ang), sinf(ang));
    }
    return;
  }
  const float* src; short* dst; int R, C, t2 = bb - 4096;
  if (t2 < 256)      { src = Wq; dst = WcatT;                        R = 1024; C = 1024; }
  else if (t2 < 320) { t2 -= 256; src = Wk; dst = WcatT + (size_t)1024*1024; R = 1024; C = 256; }
  else if (t2 < 384) { t2 -= 320; src = Wv; dst = WcatT + (size_t)1280*1024; R = 1024; C = 256; }
  else               { t2 -= 384; src = Wo; dst = WoT;               R = 1024; C = 1024; }
  const int r0 = (t2 & 15) * 64, c0 = (t2 >> 4) * 64;
  #pragma unroll
  for (int i = 0; i < 4; ++i) {
    int chunk = tid + i * 256;
    int r = chunk >> 4, cc = (chunk & 15) * 4;
    float4 v = *(const float4*)&src[(size_t)(r0 + r) * C + c0 + cc];
    T[(cc + 0) * 72 + r] = f2bf(v.x);
    T[(cc + 1) * 72 + r] = f2bf(v.y);
    T[(cc + 2) * 72 + r] = f2bf(v.z);
    T[(cc + 3) * 72 + r] = f2bf(v.w);
  }
  __syncthreads();
  #pragma unroll
  for (int i = 0; i < 2; ++i) {
    int chunk = tid + i * 256;
    int rr = chunk >> 3, kk = (chunk & 7) * 8;
    *(uint4*)&dst[(size_t)(c0 + rr) * R + r0 + kk] = *(uint4*)&T[rr * 72 + kk];
  }
}

// ---------------- bf16 MFMA GEMM: ring-2 LDS, counted-vmcnt prefetch (T4) ----------------
// Per K-step: barrier A (all waves done reading the buf about to be overwritten)
// -> STAGE(t+1) -> vmcnt(6) (t's loads done, t+1's 6 stay IN FLIGHT) ->
// barrier B -> compute(t). sched_barrier(0) fences pin ds_reads inside their
// barrier interval (scheduler cannot migrate them into the overwrite window).
template<int BMT, int BNT>
__global__ __launch_bounds__(256, 3) void gemm_bf16_t(const short* __restrict__ A,
    const short* __restrict__ BT, float* __restrict__ C, int M, int N, int K) {
  constexpr int MI = BMT / 32, NI = BNT / 32;
  static_assert(MI + NI == 6, "vmcnt literal assumes 6 loads/thread/step");
  __shared__ short As[2 * BMT * BKT];
  __shared__ short Bs[2 * BNT * BKT];
  const int tid = threadIdx.x;
  const int wave = tid >> 6, lane = tid & 63;
  const int quad = lane >> 4, l15 = lane & 15;
  const int wm = (wave >> 1) * (BMT / 2), wn = (wave & 1) * (BNT / 2);
  const int m0 = blockIdx.y * BMT, n0 = blockIdx.x * BNT;
  const int rA = wave * (BMT / 4) + (lane >> 3);
  const int rB = wave * (BNT / 4) + (lane >> 3);
  const int scol = (lane & 7) * 8;

  f32x4 acc[MI][NI] = {};

#define GSTAGE(u) do { \
    const int bi_ = (u) & 1; const int k0_ = (u) * BKT; \
    _Pragma("unroll") \
    for (int j = 0; j < MI; ++j) \
      __builtin_amdgcn_global_load_lds( \
          (const __attribute__((address_space(1))) void*)&A[(size_t)(m0 + rA + j * 8) * K + k0_ + scol], \
          (__attribute__((address_space(3))) void*)&As[bi_ * BMT * BKT + (wave * MI + j) * 512], 16, 0, 0); \
    _Pragma("unroll") \
    for (int j = 0; j < NI; ++j) \
      __builtin_amdgcn_global_load_lds( \
          (const __attribute__((address_space(1))) void*)&BT[(size_t)(n0 + rB + j * 8) * K + k0_ + scol], \
          (__attribute__((address_space(3))) void*)&Bs[bi_ * BNT * BKT + (wave * NI + j) * 512], 16, 0, 0); \
  } while (0)

  const int nk = K / BKT;
  GSTAGE(0);
  for (int t = 0; t < nk; ++t) {
    __builtin_amdgcn_sched_barrier(0);
    __builtin_amdgcn_s_barrier();          // A: all waves done reading buf[(t+1)&1]
    __builtin_amdgcn_sched_barrier(0);
    if (t + 1 < nk) {
      GSTAGE(t + 1);
      asm volatile("s_waitcnt vmcnt(6)" ::: "memory");   // t's loads done; t+1's in flight
    } else {
      asm volatile("s_waitcnt vmcnt(0)" ::: "memory");
    }
    __builtin_amdgcn_sched_barrier(0);
    __builtin_amdgcn_s_barrier();          // B: buf[t] visible to all waves
    __builtin_amdgcn_sched_barrier(0);
    const short* As_ = &As[(t & 1) * BMT * BKT];
    const short* Bs_ = &Bs[(t & 1) * BNT * BKT];
    #pragma unroll
    for (int ks = 0; ks < 2; ++ks) {
      short8 af[MI], bfr[NI];
      #pragma unroll
      for (int mi = 0; mi < MI; ++mi)
        af[mi] = *(const short8*)&As_[(wm + mi*16 + l15)*BKT + ks*32 + quad*8];
      #pragma unroll
      for (int ni = 0; ni < NI; ++ni)
        bfr[ni] = *(const short8*)&Bs_[(wn + ni*16 + l15)*BKT + ks*32 + quad*8];
      #pragma unroll
      for (int mi = 0; mi < MI; ++mi)
        #pragma unroll
        for (int ni = 0; ni < NI; ++ni)
          acc[mi][ni] = __builtin_amdgcn_mfma_f32_16x16x32_bf16(af[mi], bfr[ni], acc[mi][ni], 0, 0, 0);
    }
  }
#undef GSTAGE
  #pragma unroll
  for (int mi = 0; mi < MI; ++mi)
    #pragma unroll
    for (int ni = 0; ni < NI; ++ni)
      #pragma unroll
      for (int r = 0; r < 4; ++r)
        C[(size_t)(m0 + wm + mi*16 + quad*4 + r)*N + (n0 + wn + ni*16 + l15)] = acc[mi][ni][r];
}

// ---------------- QKV GEMM (ring-2 counted-vmcnt) + fused RoPE + fused V-transpose ----------------
__global__ __launch_bounds__(256, 3) void gemm_qkv(const short* __restrict__ A,
    const short* __restrict__ BT, const float2* __restrict__ tab,
    short* __restrict__ Qb, short* __restrict__ Kb, short* __restrict__ Vt) {
  constexpr int MI = 2, NI = 4;   // 64 x 128
  __shared__ short SM[24576];     // As[2][4096] @0, Bs[2][8192] @8192; V-transpose T[128][80] aliases
  short* As = SM;
  short* Bs = SM + 8192;
  const int tid = threadIdx.x;
  const int wave = tid >> 6, lane = tid & 63;
  const int quad = lane >> 4, l15 = lane & 15;
  const int wm = (wave >> 1) * 32, wn = (wave & 1) * 64;
  const int m0 = blockIdx.y * 64, n0 = blockIdx.x * 128;
  const int rA = wave * 16 + (lane >> 3);
  const int rB = wave * 32 + (lane >> 3);
  const int scol = (lane & 7) * 8;

  f32x4 acc[MI][NI] = {};

#define QSTAGE(u) do { \
    const int bi_ = (u) & 1; const int k0_ = (u) * BKT; \
    _Pragma("unroll") \
    for (int j = 0; j < MI; ++j) \
      __builtin_amdgcn_global_load_lds( \
          (const __attribute__((address_space(1))) void*)&A[(size_t)(m0 + rA + j * 8) * DM + k0_ + scol], \
          (__attribute__((address_space(3))) void*)&As[bi_ * 4096 + (wave * MI + j) * 512], 16, 0, 0); \
    _Pragma("unroll") \
    for (int j = 0; j < NI; ++j) \
      __builtin_amdgcn_global_load_lds( \
          (const __attribute__((address_space(1))) void*)&BT[(size_t)(n0 + rB + j * 8) * DM + k0_ + scol], \
          (__attribute__((address_space(3))) void*)&Bs[bi_ * 8192 + (wave * NI + j) * 512], 16, 0, 0); \
  } while (0)

  const int nk = DM / BKT;   // 16
  QSTAGE(0);
  for (int t = 0; t < nk; ++t) {
    __builtin_amdgcn_sched_barrier(0);
    __builtin_amdgcn_s_barrier();          // A
    __builtin_amdgcn_sched_barrier(0);
    if (t + 1 < nk) {
      QSTAGE(t + 1);
      asm volatile("s_waitcnt vmcnt(6)" ::: "memory");
    } else {
      asm volatile("s_waitcnt vmcnt(0)" ::: "memory");
    }
    __builtin_amdgcn_sched_barrier(0);
    __builtin_amdgcn_s_barrier();          // B
    __builtin_amdgcn_sched_barrier(0);
    const short* As_ = &As[(t & 1) * 4096];
    const short* Bs_ = &Bs[(t & 1) * 8192];
    #pragma unroll
    for (int ks = 0; ks < 2; ++ks) {
      short8 af[MI], bfr[NI];
      #pragma unroll
      for (int mi = 0; mi < MI; ++mi)
        af[mi] = *(const short8*)&As_[(wm + mi*16 + l15)*BKT + ks*32 + quad*8];
      #pragma unroll
      for (int ni = 0; ni < NI; ++ni)
        bfr[ni] = *(const short8*)&Bs_[(wn + ni*16 + l15)*BKT + ks*32 + quad*8];
      #pragma unroll
      for (int mi = 0; mi < MI; ++mi)
        #pragma unroll
        for (int ni = 0; ni < NI; ++ni)
          acc[mi][ni] = __builtin_amdgcn_mfma_f32_16x16x32_bf16(af[mi], bfr[ni], acc[mi][ni], 0, 0, 0);
    }
  }
#undef QSTAGE

  const int c0 = n0 + wn;                 // multiple of 64
  if (n0 < 1024) {                        // ---- Q: rope * QFOLD ----
    #pragma unroll
    for (int mi = 0; mi < MI; ++mi)
      #pragma unroll
      for (int r = 0; r < 4; ++r) {
        const int row = m0 + wm + mi*16 + quad*4 + r;
        const int s = row & (S_LEN - 1);
        #pragma unroll
        for (int ni = 0; ni < 2; ++ni) {
          const int j = ni*16 + l15;
          const float2 cn = tab[s*32 + j];
          const float x1 = acc[mi][ni][r], x2 = acc[mi][ni+2][r];
          Qb[(size_t)row*1024 + c0 + j]      = f2bf((x1*cn.x - x2*cn.y) * QFOLD);
          Qb[(size_t)row*1024 + c0 + j + 32] = f2bf((x2*cn.x + x1*cn.y) * QFOLD);
        }
      }
  } else if (n0 < 1280) {                 // ---- K: rope + XOR-swizzle ----
    const int hh = (c0 - 1024) >> 6;
    #pragma unroll
    for (int mi = 0; mi < MI; ++mi)
      #pragma unroll
      for (int r = 0; r < 4; ++r) {
        const int row = m0 + wm + mi*16 + quad*4 + r;
        const int s = row & (S_LEN - 1);
        const int sw = (s & 7) << 3;
        #pragma unroll
        for (int ni = 0; ni < 2; ++ni) {
          const int j = ni*16 + l15;
          const float2 cn = tab[s*32 + j];
          const float x1 = acc[mi][ni][r], x2 = acc[mi][ni+2][r];
          Kb[(size_t)row*256 + hh*64 + (j ^ sw)]        = f2bf(x1*cn.x - x2*cn.y);
          Kb[(size_t)row*256 + hh*64 + ((j + 32) ^ sw)] = f2bf(x2*cn.x + x1*cn.y);
        }
      }
  } else {                                // ---- V: LDS transpose -> Vt (swizzled) ----
    __syncthreads();                      // staging LDS dead; reuse as T[128 vcol][80]
    #pragma unroll
    for (int mi = 0; mi < MI; ++mi)
      #pragma unroll
      for (int ni = 0; ni < NI; ++ni) {
        short4 p;
        p.x = f2bf(acc[mi][ni][0]); p.y = f2bf(acc[mi][ni][1]);
        p.z = f2bf(acc[mi][ni][2]); p.w = f2bf(acc[mi][ni][3]);
        *(short4*)&SM[(wn + ni*16 + l15)*80 + wm + mi*16 + quad*4] = p;
      }
    __syncthreads();
    const int b_ = m0 >> 11, sbase = m0 & (S_LEN - 1);
    #pragma unroll
    for (int i = 0; i < 4; ++i) {
      const int chunk = tid + i * 256;      // [0,1024)
      const int vl = chunk >> 3;            // local vcol 0..127
      const int kk = (chunk & 7) * 8;       // 0..56
      const int vcol = (n0 - 1280) + vl;
      const int kvh = vcol >> 6, dd = vcol & 63;
      uint4 v = *(uint4*)&SM[vl*80 + kk];
      *(uint4*)&Vt[((size_t)((b_*4 + kvh)*64 + dd))*S_LEN + sbase + (kk ^ ((dd & 7) << 3))] = v;
    }
  }
}

// ---------------- causal GQA flash attention v13: heads-as-waves (round-7 verbatim, PASSED) ----------------
__global__ __launch_bounds__(256, 3) void fattn13(const short* __restrict__ Qb,
    const short* __restrict__ Kb, const short* __restrict__ Vt, short* __restrict__ Ctx) {
  __shared__ short SMEM[24576];   // 3 bufs x (K[64][64] @ +0, VT[64][64] @ +4096 shorts)
  const int idx = blockIdx.x;
  const int kk_ = (idx & 255) >> 3;
  const int jt  = (idx >> 8) ? kk_ : 63 - kk_;
  const int b   = (idx >> 2) & 1;
  const int kvh = idx & 3;
  const int tid = threadIdx.x, wav = tid >> 6, lane = tid & 63;
  const int l31 = lane & 31, hi = lane >> 5;
  const int h = kvh * 4 + wav;             // this wave's q-head
  const int sx = (l31 & 7) << 3;           // XOR-swizzle key (matches producers)
  const size_t qbase  = (size_t)b * S_LEN * 1024;
  const size_t kbase  = (size_t)b * S_LEN * 256;
  const size_t vtbase = (size_t)(b * 4 + kvh) * 64 * S_LEN;

  const short* kptr = Kb + kbase + (size_t)(tid >> 3) * 256 + kvh * 64 + (tid & 7) * 8;
  const short* vptr = Vt + vtbase + (size_t)(tid >> 3) * 2048 + (tid & 7) * 8;

#define STAGE(u) do { \
    const int bi_ = (u) % 3; \
    const short* kp_ = kptr + (size_t)(u) * 16384; \
    const short* vp_ = vptr + (u) * 64; \
    short* kd_ = &SMEM[bi_ * 8192 + tid * 8]; \
    short* vd_ = &SMEM[bi_ * 8192 + 4096 + tid * 8]; \
    _Pragma("unroll") \
    for (int i_ = 0; i_ < 2; ++i_) { \
      __builtin_amdgcn_global_load_lds((const __attribute__((address_space(1))) void*)(kp_ + i_ * 8192), \
          (__attribute__((address_space(3))) void*)(kd_ + i_ * 2048), 16, 0, 0); \
      __builtin_amdgcn_global_load_lds((const __attribute__((address_space(1))) void*)(vp_ + i_ * 65536), \
          (__attribute__((address_space(3))) void*)(vd_ + i_ * 2048), 16, 0, 0); \
    } \
  } while (0)

  const int q0 = jt * 32;
  const int ntiles = (jt >> 1) + 1;     // 64-kv units covering [0, q0+32)
  const int qg = q0 + l31;              // this lane's q column (score space)

  // Q B-frags: lane holds Q[q=l31 of tile][d = ks*16 + hi*8 + j]
  short8 qf[4];
  {
    const short* qp = &Qb[qbase + (size_t)qg * 1024 + h * 64 + hi * 8];
    #pragma unroll
    for (int ks = 0; ks < 4; ++ks) qf[ks] = *(const short8*)(qp + ks * 16);
  }

  f32x16 O0 = {}, O1 = {};
  float la0 = 0.f, la1 = 0.f, la2 = 0.f, la3 = 0.f;

  STAGE(0);
  if (ntiles > 1) STAGE(1);

  for (int t = 0; t < ntiles; ++t) {
    const int k0 = t * 64;
    const int rem = ntiles - 1 - t;
    if (rem >= 1) { asm volatile("s_waitcnt vmcnt(4)" ::: "memory"); }
    else          { asm volatile("s_waitcnt vmcnt(0)" ::: "memory"); }
    __builtin_amdgcn_sched_barrier(0);
    __builtin_amdgcn_s_barrier();
    if (t + 2 < ntiles) STAGE(t + 2);   // writes buf (t+2)%3 == (t-1)%3: reads done

    const short* ks_ = &SMEM[(t % 3) * 8192];
    const short* vs_ = &SMEM[(t % 3) * 8192 + 4096];

    // St = K Q^T over the full 64-kv unit: sc[kt][r] = S[kv=k0+kt*32+crow(r,hi)][q=qg]
    f32x16 sc[2];
    __builtin_amdgcn_s_setprio(1);
    #pragma unroll
    for (int kt = 0; kt < 2; ++kt) {
      const int r = kt * 32 + l31;
      f32x16 a = {};
      #pragma unroll
      for (int ks2 = 0; ks2 < 4; ++ks2) {
        short8 kf = *(const short8*)&ks_[r * 64 + ((ks2 * 16 + hi * 8) ^ sx)];
        a = __builtin_amdgcn_mfma_f32_32x32x16_bf16(kf, qf[ks2], a, 0, 0, 0);
      }
      sc[kt] = a;
    }
    __builtin_amdgcn_s_setprio(0);

    if (t == ntiles - 1) {
      #pragma unroll
      for (int kt = 0; kt < 2; ++kt)
        #pragma unroll
        for (int r = 0; r < 16; ++r) {
          const int kvg = k0 + kt * 32 + (r & 3) + 8 * (r >> 2) + 4 * hi;
          if (kvg > qg) sc[kt][r] = -1e30f;
        }
    }

    // no-max softmax: p = exp2(s); PV A-frags in-register (T12):
    // af[s] = P[q=l31][kv_local = s*16 + hi*8 + j], s = kt*2 + st
    short8 af[4];
    #pragma unroll
    for (int kt = 0; kt < 2; ++kt) {
      #pragma unroll
      for (int r = 0; r < 16; ++r) sc[kt][r] = exp2f(sc[kt][r]);
      la0 += (sc[kt][0] + sc[kt][1]) + (sc[kt][2] + sc[kt][3]);
      la1 += (sc[kt][4] + sc[kt][5]) + (sc[kt][6] + sc[kt][7]);
      la2 += (sc[kt][8] + sc[kt][9]) + (sc[kt][10] + sc[kt][11]);
      la3 += (sc[kt][12] + sc[kt][13]) + (sc[kt][14] + sc[kt][15]);
      #pragma unroll
      for (int st = 0; st < 2; ++st) {
        uint32_t x0 = pk2(sc[kt][st * 8 + 0], sc[kt][st * 8 + 1]);
        uint32_t x1 = pk2(sc[kt][st * 8 + 2], sc[kt][st * 8 + 3]);
        uint32_t x2 = pk2(sc[kt][st * 8 + 4], sc[kt][st * 8 + 5]);
        uint32_t x3 = pk2(sc[kt][st * 8 + 6], sc[kt][st * 8 + 7]);
        asm("v_permlane32_swap_b32 %0, %1" : "+v"(x0), "+v"(x2));
        asm("v_permlane32_swap_b32 %0, %1" : "+v"(x1), "+v"(x3));
        union { short8 s8; uint32_t u[4]; } cv;
        cv.u[0] = x0; cv.u[1] = x1; cv.u[2] = x2; cv.u[3] = x3;
        af[kt * 2 + st] = cv.s8;
      }
    }

    // O += P V over the full 64-kv unit: B-frag from V^T LDS rows d=l31 / 32+l31
    __builtin_amdgcn_s_setprio(1);
    #pragma unroll
    for (int s = 0; s < 4; ++s) {
      const int co = s * 16 + hi * 8;
      short8 bv0 = *(const short8*)&vs_[l31 * 64 + (co ^ sx)];
      O0 = __builtin_amdgcn_mfma_f32_32x32x16_bf16(af[s], bv0, O0, 0, 0, 0);
      short8 bv1 = *(const short8*)&vs_[(32 + l31) * 64 + (co ^ sx)];
      O1 = __builtin_amdgcn_mfma_f32_32x32x16_bf16(af[s], bv1, O1, 0, 0, 0);
    }
    __builtin_amdgcn_s_setprio(0);
  }

  // ---- finalize: wave owns full kv for its head -> no cross-wave combine ----
  float ll = (la0 + la1) + (la2 + la3);
  ll += __shfl_xor(ll, 32, 64);   // lane: l for q = q0 + l31 (full kv sum)
  const float inv = 1.0f / ll;
  #pragma unroll
  for (int r = 0; r < 16; ++r) {
    const int crow = (r & 3) + 8 * (r >> 2) + 4 * hi;
    const float invr = __shfl(inv, crow, 64);
    const size_t o = qbase + (size_t)(q0 + crow) * 1024 + h * 64;
    Ctx[o + l31]      = f2bf(O0[r] * invr);
    Ctx[o + 32 + l31] = f2bf(O1[r] * invr);
  }
#undef STAGE
}

extern "C" void kernel_launch(void* const* d_in, const int* in_sizes, int n_in,
                              void* d_out, int out_size, void* d_ws, size_t ws_size,
                              hipStream_t stream) {
  const float* x  = (const float*)d_in[0];
  const float* Wq = (const float*)d_in[1];
  const float* Wk = (const float*)d_in[2];
  const float* Wv = (const float*)d_in[3];
  const float* Wo = (const float*)d_in[4];
  float* out = (float*)d_out;

  char* w = (char*)d_ws;
  short*  Xb    = (short*)w;   w += (size_t)MROWS * DM * 2;
  short*  WcatT = (short*)w;   w += (size_t)NQKV * DM * 2;
  short*  WoT   = (short*)w;   w += (size_t)DM * DM * 2;
  short*  Qbuf  = (short*)w;   w += (size_t)MROWS * DM * 2;
  short*  Kbuf  = (short*)w;   w += (size_t)MROWS * 256 * 2;
  short*  Vt    = (short*)w;   w += (size_t)8 * 64 * S_LEN * 2;
  short*  Ctx   = (short*)w;   w += (size_t)MROWS * DM * 2;
  float2* tab   = (float2*)w;  w += (size_t)S_LEN * 32 * 8;

  prep<<<dim3(4800), dim3(256), 0, stream>>>(x, Wq, Wk, Wv, Wo, Xb, WcatT, WoT, tab);

  // QKV GEMM with fused rope + fused V-transpose epilogue (ring-2 counted vmcnt)
  gemm_qkv<<<dim3(NQKV / 128, MROWS / 64), dim3(256), 0, stream>>>(Xb, WcatT, tab, Qbuf, Kbuf, Vt);
  fattn13<<<dim3(512), dim3(256), 0, stream>>>(Qbuf, Kbuf, Vt, Ctx);
  gemm_bf16_t<64,128><<<dim3(DM / 128, MROWS / 64), dim3(256), 0, stream>>>(Ctx, WoT, out, MROWS, DM, DM);
}